// Round 1
// baseline (4138.595 us; speedup 1.0000x reference)
//
#include <hip/hip_runtime.h>
#include <hip/hip_bf16.h>

// ---------------------------------------------------------------------------
// Problem constants (from reference setup_inputs)
// ---------------------------------------------------------------------------
#define N0 100000
#define E0C 1600000
#define N1 100000
#define E1C 1600000
#define GCONST 512
#define F0C 93
#define F1C 43
#define OC0 (F0C * 10)   // 930
#define OC1 (F1C * 10)   // 430
#define BN_EPS 1e-5f

// ---------------------------------------------------------------------------
// copy kernel (float4)
// ---------------------------------------------------------------------------
__global__ __launch_bounds__(256) void copy4_kernel(float4* __restrict__ dst,
                                                    const float4* __restrict__ src,
                                                    int n4) {
    int i = blockIdx.x * 256 + threadIdx.x;
    if (i < n4) dst[i] = src[i];
}

// ---------------------------------------------------------------------------
// graph boundary search: starts[g] = lower_bound(batch, g); starts[G] = N
// ---------------------------------------------------------------------------
__global__ __launch_bounds__(256) void find_starts_kernel(const int* __restrict__ batch,
                                                          int N, int G,
                                                          int* __restrict__ starts) {
    int g = blockIdx.x * 256 + threadIdx.x;
    if (g > G) return;
    if (g == G) { starts[G] = N; return; }
    int lo = 0, hi = N;
    while (lo < hi) {
        int mid = (lo + hi) >> 1;
        if (batch[mid] < g) lo = mid + 1; else hi = mid;
    }
    starts[g] = lo;
}

// ---------------------------------------------------------------------------
// scatter-add: t[dst] += x[src] for each edge. t pre-initialized with x
// (GIN identity term). FPAD = F rounded up to pow2-ish subgroup.
// ---------------------------------------------------------------------------
template<int FPAD>
__global__ __launch_bounds__(256) void scatter_add_kernel(float* __restrict__ t,
                                                          const float* __restrict__ x,
                                                          const int* __restrict__ ei,
                                                          int E, int F) {
    constexpr int EPB = 256 / FPAD;
    int e = blockIdx.x * EPB + threadIdx.x / FPAD;
    int f = threadIdx.x % FPAD;
    if (e >= E || f >= F) return;
    int src = ei[e];
    int dst = ei[E + e];
    atomicAdd(&t[(size_t)dst * F + f], x[(size_t)src * F + f]);
}

// ---------------------------------------------------------------------------
// generic fp32 GEMM: C = A[MxK] @ B[KxN] + bias, optional relu.
// 64x64 tile, 256 threads, 4x4 register micro-tile, K-tile 16.
// ---------------------------------------------------------------------------
__global__ __launch_bounds__(256) void gemm_bias_kernel(const float* __restrict__ A,
                                                        const float* __restrict__ B,
                                                        const float* __restrict__ bias,
                                                        float* __restrict__ C,
                                                        int M, int N, int K, int relu) {
    __shared__ float As[16][64];
    __shared__ float Bs[16][64];
    int tid = threadIdx.x;
    int tx = tid & 15, ty = tid >> 4;
    int m0 = blockIdx.y * 64, n0 = blockIdx.x * 64;
    float acc[4][4] = {};
    for (int k0 = 0; k0 < K; k0 += 16) {
#pragma unroll
        for (int i = 0; i < 4; ++i) {
            int lin = tid + i * 256;
            int m = lin >> 4, k = lin & 15;
            int gm = m0 + m, gk = k0 + k;
            As[k][m] = (gm < M && gk < K) ? A[(size_t)gm * K + gk] : 0.f;
        }
#pragma unroll
        for (int i = 0; i < 4; ++i) {
            int lin = tid + i * 256;
            int n = lin & 63, k = lin >> 6;
            int gn = n0 + n, gk = k0 + k;
            Bs[k][n] = (gk < K && gn < N) ? B[(size_t)gk * N + gn] : 0.f;
        }
        __syncthreads();
#pragma unroll
        for (int k = 0; k < 16; ++k) {
            float a[4], b[4];
#pragma unroll
            for (int i = 0; i < 4; ++i) a[i] = As[k][ty * 4 + i];
#pragma unroll
            for (int j = 0; j < 4; ++j) b[j] = Bs[k][tx * 4 + j];
#pragma unroll
            for (int i = 0; i < 4; ++i)
#pragma unroll
                for (int j = 0; j < 4; ++j)
                    acc[i][j] = fmaf(a[i], b[j], acc[i][j]);
        }
        __syncthreads();
    }
#pragma unroll
    for (int i = 0; i < 4; ++i) {
        int gm = m0 + ty * 4 + i;
        if (gm >= M) continue;
#pragma unroll
        for (int j = 0; j < 4; ++j) {
            int gn = n0 + tx * 4 + j;
            if (gn >= N) continue;
            float v = acc[i][j] + bias[gn];
            if (relu) v = fmaxf(v, 0.f);
            C[(size_t)gm * N + gn] = v;
        }
    }
}

// ---------------------------------------------------------------------------
// fused conv2 matmul + relu + mean/max pool.
// thread = output column (one of OC), block.y = graph. W column in registers,
// t rows are block-uniform reads (expected to lower to s_load + v_fmac s,v,v).
// pooled layout: [G][2*OC]  (mean | max) to match g*_w1's K ordering.
// ---------------------------------------------------------------------------
template<int F>
__global__ __launch_bounds__(256) void conv2_pool_kernel(const float* __restrict__ t,
                                                         const float* __restrict__ W,
                                                         const float* __restrict__ bias,
                                                         const int* __restrict__ starts,
                                                         float* __restrict__ pooled,
                                                         int OC) {
    int col = blockIdx.x * 256 + threadIdx.x;
    int g = blockIdx.y;
    int cc = (col < OC) ? col : (OC - 1);
    float wreg[F];
#pragma unroll
    for (int k = 0; k < F; ++k) wreg[k] = W[(size_t)k * OC + cc];
    float bb = bias[cc];
    int s = starts[g], e = starts[g + 1];
    float sum = 0.f, mx = 0.f;
    for (int n = s; n < e; ++n) {
        const float* __restrict__ tr = t + (size_t)n * F;
        float a0 = 0.f, a1 = 0.f, a2 = 0.f, a3 = 0.f;
#pragma unroll
        for (int k = 0; k + 3 < F; k += 4) {
            a0 = fmaf(wreg[k + 0], tr[k + 0], a0);
            a1 = fmaf(wreg[k + 1], tr[k + 1], a1);
            a2 = fmaf(wreg[k + 2], tr[k + 2], a2);
            a3 = fmaf(wreg[k + 3], tr[k + 3], a3);
        }
#pragma unroll
        for (int k = F & ~3; k < F; ++k) a0 = fmaf(wreg[k], tr[k], a0);
        float o = bb + (a0 + a1) + (a2 + a3);
        o = fmaxf(o, 0.f);
        sum += o;
        mx = fmaxf(mx, o);
    }
    int cnt = e - s;
    float mean = sum / (float)(cnt > 0 ? cnt : 1);
    if (col < OC) {
        size_t base = (size_t)g * (size_t)(2 * OC);
        pooled[base + col] = mean;
        pooled[base + OC + col] = mx;
    }
}

// ---------------------------------------------------------------------------
// batchnorm stats (population mean/var over rows, per column)
// ---------------------------------------------------------------------------
__global__ __launch_bounds__(256) void bn_stats_kernel(const float* __restrict__ p,
                                                       int rows, int cols,
                                                       float* __restrict__ mean,
                                                       float* __restrict__ inv) {
    int c = blockIdx.x;
    float s = 0.f, s2 = 0.f;
    for (int r = threadIdx.x; r < rows; r += 256) {
        float v = p[(size_t)r * cols + c];
        s += v;
        s2 += v * v;
    }
    __shared__ float ls[256], ls2[256];
    ls[threadIdx.x] = s;
    ls2[threadIdx.x] = s2;
    __syncthreads();
    for (int st = 128; st > 0; st >>= 1) {
        if (threadIdx.x < st) {
            ls[threadIdx.x] += ls[threadIdx.x + st];
            ls2[threadIdx.x] += ls2[threadIdx.x + st];
        }
        __syncthreads();
    }
    if (threadIdx.x == 0) {
        float m = ls[0] / (float)rows;
        float var = ls2[0] / (float)rows - m * m;
        mean[c] = m;
        inv[c] = 1.f / sqrtf(var + BN_EPS);
    }
}

__global__ __launch_bounds__(256) void bn_apply_kernel(const float* __restrict__ p,
                                                       const float* __restrict__ gamma,
                                                       const float* __restrict__ beta,
                                                       const float* __restrict__ mean,
                                                       const float* __restrict__ inv,
                                                       float* __restrict__ outp,
                                                       int total, int cols) {
    int i = blockIdx.x * 256 + threadIdx.x;
    if (i >= total) return;
    int c = i & (cols - 1);  // cols = 512 (pow2)
    outp[i] = gamma[c] * (p[i] - mean[c]) * inv[c] + beta[c];
}

// ---------------------------------------------------------------------------
// launch
// ---------------------------------------------------------------------------
static inline int ceildiv(int a, int b) { return (a + b - 1) / b; }

extern "C" void kernel_launch(void* const* d_in, const int* in_sizes, int n_in,
                              void* d_out, int out_size, void* d_ws, size_t ws_size,
                              hipStream_t stream) {
    const float* x0   = (const float*)d_in[0];
    const float* x1   = (const float*)d_in[1];
    const int*   ei0  = (const int*)d_in[2];
    const int*   ei1  = (const int*)d_in[3];
    const int*   bat0 = (const int*)d_in[4];
    const int*   bat1 = (const int*)d_in[5];
    const float* w_c1 = (const float*)d_in[6];
    const float* b_c1 = (const float*)d_in[7];
    const float* w_c2 = (const float*)d_in[8];
    const float* b_c2 = (const float*)d_in[9];
    const float* w_c3 = (const float*)d_in[10];
    const float* b_c3 = (const float*)d_in[11];
    const float* w_c4 = (const float*)d_in[12];
    const float* b_c4 = (const float*)d_in[13];
    const float* g0_w1 = (const float*)d_in[14];
    const float* g0_b1 = (const float*)d_in[15];
    const float* g0_w2 = (const float*)d_in[16];
    const float* g0_b2 = (const float*)d_in[17];
    const float* g0_bn_g = (const float*)d_in[18];
    const float* g0_bn_b = (const float*)d_in[19];
    const float* g1_w1 = (const float*)d_in[20];
    const float* g1_b1 = (const float*)d_in[21];
    const float* g1_w2 = (const float*)d_in[22];
    const float* g1_b2 = (const float*)d_in[23];
    const float* g1_bn_g = (const float*)d_in[24];
    const float* g1_bn_b = (const float*)d_in[25];
    const float* f0_w1 = (const float*)d_in[26];
    const float* f0_b1 = (const float*)d_in[27];
    const float* f0_w2 = (const float*)d_in[28];
    const float* f0_b2 = (const float*)d_in[29];
    const float* f1_w1 = (const float*)d_in[30];
    const float* f1_b1 = (const float*)d_in[31];
    const float* f1_w2 = (const float*)d_in[32];
    const float* f1_b2 = (const float*)d_in[33];

    float* out = (float*)d_out;
    // d_out layout: z [512*2] | x_g_0 [512*512] | x_g_1 [512*512] | z1 [512*2]
    float* out_z   = out;
    float* out_xg0 = out + 1024;
    float* out_xg1 = out + 1024 + 262144;
    float* out_z1  = out + 1024 + 262144 + 262144;

    // workspace carve (floats)
    float* ws = (float*)d_ws;
    size_t off = 0;
    auto alloc = [&](size_t n) { float* p = ws + off; off += n; return p; };
    float* t       = alloc((size_t)N0 * F0C);        // 9.3M, reused by both branches
    float* y1      = alloc((size_t)N0 * F0C);        // 9.3M
    float* pooled0 = alloc((size_t)GCONST * 2 * OC0);
    float* pooled1 = alloc((size_t)GCONST * 2 * OC1);
    float* m1      = alloc((size_t)GCONST * 1024);
    float* pbn     = alloc((size_t)GCONST * 512);
    float* hbuf    = alloc((size_t)GCONST * 256);
    float* meanb   = alloc(512);
    float* invb    = alloc(512);
    int*   starts0 = (int*)alloc(520);
    int*   starts1 = (int*)alloc(520);

    const int G = GCONST;

    // =========================== branch 0 (F=93) ===========================
    {
        const int N = N0, F = F0C, E = E0C, OC = OC0;
        int n4 = (N * F) / 4;
        copy4_kernel<<<ceildiv(n4, 256), 256, 0, stream>>>((float4*)t, (const float4*)x0, n4);
        find_starts_kernel<<<3, 256, 0, stream>>>(bat0, N, G, starts0);
        scatter_add_kernel<128><<<ceildiv(E, 2), 256, 0, stream>>>(t, x0, ei0, E, F);
        // y1 = relu((x+agg) @ w_c1 + b_c1)
        gemm_bias_kernel<<<dim3(ceildiv(F, 64), ceildiv(N, 64)), 256, 0, stream>>>(
            t, w_c1, b_c1, y1, N, F, F, 1);
        copy4_kernel<<<ceildiv(n4, 256), 256, 0, stream>>>((float4*)t, (const float4*)y1, n4);
        scatter_add_kernel<128><<<ceildiv(E, 2), 256, 0, stream>>>(t, y1, ei0, E, F);
        // fused conv2 + relu + mean/max pool
        conv2_pool_kernel<F0C><<<dim3(ceildiv(OC, 256), G), 256, 0, stream>>>(
            t, w_c2, b_c2, starts0, pooled0, OC);
        // MLP
        gemm_bias_kernel<<<dim3(1024 / 64, G / 64), 256, 0, stream>>>(
            pooled0, g0_w1, g0_b1, m1, G, 1024, 2 * OC, 1);
        gemm_bias_kernel<<<dim3(512 / 64, G / 64), 256, 0, stream>>>(
            m1, g0_w2, g0_b2, pbn, G, 512, 1024, 0);
        bn_stats_kernel<<<512, 256, 0, stream>>>(pbn, G, 512, meanb, invb);
        bn_apply_kernel<<<ceildiv(G * 512, 256), 256, 0, stream>>>(
            pbn, g0_bn_g, g0_bn_b, meanb, invb, out_xg0, G * 512, 512);
        // head
        gemm_bias_kernel<<<dim3(256 / 64, G / 64), 256, 0, stream>>>(
            out_xg0, f0_w1, f0_b1, hbuf, G, 256, 512, 1);
        gemm_bias_kernel<<<dim3(1, G / 64), 256, 0, stream>>>(
            hbuf, f0_w2, f0_b2, out_z, G, 2, 256, 0);
    }

    // =========================== branch 1 (F=43) ===========================
    {
        const int N = N1, F = F1C, E = E1C, OC = OC1;
        int n4 = (N * F) / 4;
        copy4_kernel<<<ceildiv(n4, 256), 256, 0, stream>>>((float4*)t, (const float4*)x1, n4);
        find_starts_kernel<<<3, 256, 0, stream>>>(bat1, N, G, starts1);
        scatter_add_kernel<64><<<ceildiv(E, 4), 256, 0, stream>>>(t, x1, ei1, E, F);
        gemm_bias_kernel<<<dim3(ceildiv(F, 64), ceildiv(N, 64)), 256, 0, stream>>>(
            t, w_c3, b_c3, y1, N, F, F, 1);
        copy4_kernel<<<ceildiv(n4, 256), 256, 0, stream>>>((float4*)t, (const float4*)y1, n4);
        scatter_add_kernel<64><<<ceildiv(E, 4), 256, 0, stream>>>(t, y1, ei1, E, F);
        conv2_pool_kernel<F1C><<<dim3(ceildiv(OC, 256), G), 256, 0, stream>>>(
            t, w_c4, b_c4, starts1, pooled1, OC);
        gemm_bias_kernel<<<dim3(1024 / 64, G / 64), 256, 0, stream>>>(
            pooled1, g1_w1, g1_b1, m1, G, 1024, 2 * OC, 1);
        gemm_bias_kernel<<<dim3(512 / 64, G / 64), 256, 0, stream>>>(
            m1, g1_w2, g1_b2, pbn, G, 512, 1024, 0);
        bn_stats_kernel<<<512, 256, 0, stream>>>(pbn, G, 512, meanb, invb);
        bn_apply_kernel<<<ceildiv(G * 512, 256), 256, 0, stream>>>(
            pbn, g1_bn_g, g1_bn_b, meanb, invb, out_xg1, G * 512, 512);
        gemm_bias_kernel<<<dim3(256 / 64, G / 64), 256, 0, stream>>>(
            out_xg1, f1_w1, f1_b1, hbuf, G, 256, 512, 1);
        gemm_bias_kernel<<<dim3(1, G / 64), 256, 0, stream>>>(
            hbuf, f1_w2, f1_b2, out_z1, G, 2, 256, 0);
    }
}

// Round 2
// 3795.809 us; speedup vs baseline: 1.0903x; 1.0903x over previous
//
#include <hip/hip_runtime.h>
#include <hip/hip_bf16.h>

// ---------------------------------------------------------------------------
// Problem constants (from reference setup_inputs)
// ---------------------------------------------------------------------------
#define N0 100000
#define E0C 1600000
#define N1 100000
#define E1C 1600000
#define GCONST 512
#define F0C 93
#define F1C 43
#define OC0 (F0C * 10)   // 930
#define OC1 (F1C * 10)   // 430
#define BN_EPS 1e-5f

// ---------------------------------------------------------------------------
// zero ints
// ---------------------------------------------------------------------------
__global__ __launch_bounds__(256) void zero_int_kernel(int* __restrict__ p, int n) {
    int i = blockIdx.x * 256 + threadIdx.x;
    if (i < n) p[i] = 0;
}

// ---------------------------------------------------------------------------
// graph boundary search: starts[g] = lower_bound(batch, g); starts[G] = N
// ---------------------------------------------------------------------------
__global__ __launch_bounds__(256) void find_starts_kernel(const int* __restrict__ batch,
                                                          int N, int G,
                                                          int* __restrict__ starts) {
    int g = blockIdx.x * 256 + threadIdx.x;
    if (g > G) return;
    if (g == G) { starts[G] = N; return; }
    int lo = 0, hi = N;
    while (lo < hi) {
        int mid = (lo + hi) >> 1;
        if (batch[mid] < g) lo = mid + 1; else hi = mid;
    }
    starts[g] = lo;
}

// ---------------------------------------------------------------------------
// CSR build: histogram of dst, scan, fill col with src per dst bucket
// ---------------------------------------------------------------------------
__global__ __launch_bounds__(256) void hist_kernel(const int* __restrict__ ei,
                                                   int E, int* __restrict__ deg) {
    int e = blockIdx.x * 256 + threadIdx.x;
    if (e >= E) return;
    atomicAdd(&deg[ei[E + e]], 1);   // dst row
}

__global__ __launch_bounds__(1024) void scan_kernel(const int* __restrict__ deg,
                                                    int N, int E,
                                                    int* __restrict__ rowptr,
                                                    int* __restrict__ cursor) {
    __shared__ int part[1024];
    int tid = threadIdx.x;
    int chunk = (N + 1023) / 1024;
    int s = tid * chunk;
    int e = s + chunk < N ? s + chunk : N;
    int sum = 0;
    for (int i = s; i < e; ++i) sum += deg[i];
    part[tid] = sum;
    __syncthreads();
    // inclusive Hillis-Steele scan over partials
    for (int off = 1; off < 1024; off <<= 1) {
        int add = (tid >= off) ? part[tid - off] : 0;
        __syncthreads();
        part[tid] += add;
        __syncthreads();
    }
    int run = part[tid] - sum;  // exclusive prefix of this chunk
    for (int i = s; i < e; ++i) {
        rowptr[i] = run;
        cursor[i] = run;
        run += deg[i];
    }
    if (tid == 1023) rowptr[N] = E;
}

__global__ __launch_bounds__(256) void fill_kernel(const int* __restrict__ ei,
                                                   int E,
                                                   int* __restrict__ cursor,
                                                   int* __restrict__ col) {
    int e = blockIdx.x * 256 + threadIdx.x;
    if (e >= E) return;
    int src = ei[e];
    int dst = ei[E + e];
    int pos = atomicAdd(&cursor[dst], 1);
    col[pos] = src;
}

// ---------------------------------------------------------------------------
// CSR gather-aggregate: t[i] = x[i] + sum_{j in row(i)} x[col[j]]
// block = (256/FPAD) nodes x FPAD feature-lanes; coalesced row reads.
// ---------------------------------------------------------------------------
template<int F, int FPAD>
__global__ __launch_bounds__(256) void gather_agg_kernel(float* __restrict__ t,
                                                         const float* __restrict__ x,
                                                         const int* __restrict__ rowptr,
                                                         const int* __restrict__ col,
                                                         int N) {
    constexpr int NPB = 256 / FPAD;
    int node = blockIdx.x * NPB + threadIdx.x / FPAD;
    int f = threadIdx.x % FPAD;
    if (node >= N || f >= F) return;
    float acc = x[(size_t)node * F + f];
    int s = rowptr[node], e = rowptr[node + 1];
    for (int j = s; j < e; ++j) {
        int src = col[j];
        acc += x[(size_t)src * F + f];
    }
    t[(size_t)node * F + f] = acc;
}

// ---------------------------------------------------------------------------
// generic fp32 GEMM: C = A[MxK] @ B[KxN] + bias, optional relu.
// 64x64 tile, 256 threads, 4x4 register micro-tile, K-tile 16.
// ---------------------------------------------------------------------------
__global__ __launch_bounds__(256) void gemm_bias_kernel(const float* __restrict__ A,
                                                        const float* __restrict__ B,
                                                        const float* __restrict__ bias,
                                                        float* __restrict__ C,
                                                        int M, int N, int K, int relu) {
    __shared__ float As[16][64];
    __shared__ float Bs[16][64];
    int tid = threadIdx.x;
    int tx = tid & 15, ty = tid >> 4;
    int m0 = blockIdx.y * 64, n0 = blockIdx.x * 64;
    float acc[4][4] = {};
    for (int k0 = 0; k0 < K; k0 += 16) {
#pragma unroll
        for (int i = 0; i < 4; ++i) {
            int lin = tid + i * 256;
            int m = lin >> 4, k = lin & 15;
            int gm = m0 + m, gk = k0 + k;
            As[k][m] = (gm < M && gk < K) ? A[(size_t)gm * K + gk] : 0.f;
        }
#pragma unroll
        for (int i = 0; i < 4; ++i) {
            int lin = tid + i * 256;
            int n = lin & 63, k = lin >> 6;
            int gn = n0 + n, gk = k0 + k;
            Bs[k][n] = (gk < K && gn < N) ? B[(size_t)gk * N + gn] : 0.f;
        }
        __syncthreads();
#pragma unroll
        for (int k = 0; k < 16; ++k) {
            float a[4], b[4];
#pragma unroll
            for (int i = 0; i < 4; ++i) a[i] = As[k][ty * 4 + i];
#pragma unroll
            for (int j = 0; j < 4; ++j) b[j] = Bs[k][tx * 4 + j];
#pragma unroll
            for (int i = 0; i < 4; ++i)
#pragma unroll
                for (int j = 0; j < 4; ++j)
                    acc[i][j] = fmaf(a[i], b[j], acc[i][j]);
        }
        __syncthreads();
    }
#pragma unroll
    for (int i = 0; i < 4; ++i) {
        int gm = m0 + ty * 4 + i;
        if (gm >= M) continue;
#pragma unroll
        for (int j = 0; j < 4; ++j) {
            int gn = n0 + tx * 4 + j;
            if (gn >= N) continue;
            float v = acc[i][j] + bias[gn];
            if (relu) v = fmaxf(v, 0.f);
            C[(size_t)gm * N + gn] = v;
        }
    }
}

// ---------------------------------------------------------------------------
// fused conv2 matmul + relu + mean/max pool.
// thread = output column, block.y = graph. W column in registers.
// pooled layout: [G][2*OC]  (mean | max)
// ---------------------------------------------------------------------------
template<int F>
__global__ __launch_bounds__(256) void conv2_pool_kernel(const float* __restrict__ t,
                                                         const float* __restrict__ W,
                                                         const float* __restrict__ bias,
                                                         const int* __restrict__ starts,
                                                         float* __restrict__ pooled,
                                                         int OC) {
    int col = blockIdx.x * 256 + threadIdx.x;
    int g = blockIdx.y;
    int cc = (col < OC) ? col : (OC - 1);
    float wreg[F];
#pragma unroll
    for (int k = 0; k < F; ++k) wreg[k] = W[(size_t)k * OC + cc];
    float bb = bias[cc];
    int s = starts[g], e = starts[g + 1];
    float sum = 0.f, mx = 0.f;
    for (int n = s; n < e; ++n) {
        const float* __restrict__ tr = t + (size_t)n * F;
        float a0 = 0.f, a1 = 0.f, a2 = 0.f, a3 = 0.f;
#pragma unroll
        for (int k = 0; k + 3 < F; k += 4) {
            a0 = fmaf(wreg[k + 0], tr[k + 0], a0);
            a1 = fmaf(wreg[k + 1], tr[k + 1], a1);
            a2 = fmaf(wreg[k + 2], tr[k + 2], a2);
            a3 = fmaf(wreg[k + 3], tr[k + 3], a3);
        }
#pragma unroll
        for (int k = F & ~3; k < F; ++k) a0 = fmaf(wreg[k], tr[k], a0);
        float o = bb + (a0 + a1) + (a2 + a3);
        o = fmaxf(o, 0.f);
        sum += o;
        mx = fmaxf(mx, o);
    }
    int cnt = e - s;
    float mean = sum / (float)(cnt > 0 ? cnt : 1);
    if (col < OC) {
        size_t base = (size_t)g * (size_t)(2 * OC);
        pooled[base + col] = mean;
        pooled[base + OC + col] = mx;
    }
}

// ---------------------------------------------------------------------------
// batchnorm stats + apply
// ---------------------------------------------------------------------------
__global__ __launch_bounds__(256) void bn_stats_kernel(const float* __restrict__ p,
                                                       int rows, int cols,
                                                       float* __restrict__ mean,
                                                       float* __restrict__ inv) {
    int c = blockIdx.x;
    float s = 0.f, s2 = 0.f;
    for (int r = threadIdx.x; r < rows; r += 256) {
        float v = p[(size_t)r * cols + c];
        s += v;
        s2 += v * v;
    }
    __shared__ float ls[256], ls2[256];
    ls[threadIdx.x] = s;
    ls2[threadIdx.x] = s2;
    __syncthreads();
    for (int st = 128; st > 0; st >>= 1) {
        if (threadIdx.x < st) {
            ls[threadIdx.x] += ls[threadIdx.x + st];
            ls2[threadIdx.x] += ls2[threadIdx.x + st];
        }
        __syncthreads();
    }
    if (threadIdx.x == 0) {
        float m = ls[0] / (float)rows;
        float var = ls2[0] / (float)rows - m * m;
        mean[c] = m;
        inv[c] = 1.f / sqrtf(var + BN_EPS);
    }
}

__global__ __launch_bounds__(256) void bn_apply_kernel(const float* __restrict__ p,
                                                       const float* __restrict__ gamma,
                                                       const float* __restrict__ beta,
                                                       const float* __restrict__ mean,
                                                       const float* __restrict__ inv,
                                                       float* __restrict__ outp,
                                                       int total, int cols) {
    int i = blockIdx.x * 256 + threadIdx.x;
    if (i >= total) return;
    int c = i & (cols - 1);  // cols = 512 (pow2)
    outp[i] = gamma[c] * (p[i] - mean[c]) * inv[c] + beta[c];
}

// ---------------------------------------------------------------------------
// launch
// ---------------------------------------------------------------------------
static inline int ceildiv(int a, int b) { return (a + b - 1) / b; }

extern "C" void kernel_launch(void* const* d_in, const int* in_sizes, int n_in,
                              void* d_out, int out_size, void* d_ws, size_t ws_size,
                              hipStream_t stream) {
    const float* x0   = (const float*)d_in[0];
    const float* x1   = (const float*)d_in[1];
    const int*   ei0  = (const int*)d_in[2];
    const int*   ei1  = (const int*)d_in[3];
    const int*   bat0 = (const int*)d_in[4];
    const int*   bat1 = (const int*)d_in[5];
    const float* w_c1 = (const float*)d_in[6];
    const float* b_c1 = (const float*)d_in[7];
    const float* w_c2 = (const float*)d_in[8];
    const float* b_c2 = (const float*)d_in[9];
    const float* w_c3 = (const float*)d_in[10];
    const float* b_c3 = (const float*)d_in[11];
    const float* w_c4 = (const float*)d_in[12];
    const float* b_c4 = (const float*)d_in[13];
    const float* g0_w1 = (const float*)d_in[14];
    const float* g0_b1 = (const float*)d_in[15];
    const float* g0_w2 = (const float*)d_in[16];
    const float* g0_b2 = (const float*)d_in[17];
    const float* g0_bn_g = (const float*)d_in[18];
    const float* g0_bn_b = (const float*)d_in[19];
    const float* g1_w1 = (const float*)d_in[20];
    const float* g1_b1 = (const float*)d_in[21];
    const float* g1_w2 = (const float*)d_in[22];
    const float* g1_b2 = (const float*)d_in[23];
    const float* g1_bn_g = (const float*)d_in[24];
    const float* g1_bn_b = (const float*)d_in[25];
    const float* f0_w1 = (const float*)d_in[26];
    const float* f0_b1 = (const float*)d_in[27];
    const float* f0_w2 = (const float*)d_in[28];
    const float* f0_b2 = (const float*)d_in[29];
    const float* f1_w1 = (const float*)d_in[30];
    const float* f1_b1 = (const float*)d_in[31];
    const float* f1_w2 = (const float*)d_in[32];
    const float* f1_b2 = (const float*)d_in[33];

    float* out = (float*)d_out;
    // d_out layout: z [512*2] | x_g_0 [512*512] | x_g_1 [512*512] | z1 [512*2]
    float* out_z   = out;
    float* out_xg0 = out + 1024;
    float* out_xg1 = out + 1024 + 262144;
    float* out_z1  = out + 1024 + 262144 + 262144;

    // workspace carve (floats)
    float* ws = (float*)d_ws;
    size_t off = 0;
    auto alloc = [&](size_t n) { float* p = ws + off; off += n; return p; };
    float* t  = alloc((size_t)N0 * F0C);   // 9.3M
    float* y1 = alloc((size_t)N0 * F0C);   // 9.3M
    // Union region C: CSR (graph phase) aliases MLP temps (dense phase).
    // CSR is dead before conv2_pool writes pooled -> safe.
    size_t csr_floats = (size_t)N0 + (N0 + 1) + N0 + E0C;        // 1.90M
    size_t mlp_floats = (size_t)GCONST * 2 * OC0 + (size_t)GCONST * 2 * OC1 +
                        (size_t)GCONST * 1024 + (size_t)GCONST * 512 +
                        (size_t)GCONST * 256;                     // 2.31M
    float* regionC = alloc(csr_floats > mlp_floats ? csr_floats : mlp_floats);
    int* deg    = (int*)regionC;
    int* rowptr = deg + N0;
    int* cursor = rowptr + (N0 + 1);
    int* colb   = cursor + N0;
    float* pooled0 = regionC;
    float* pooled1 = pooled0 + (size_t)GCONST * 2 * OC0;
    float* m1      = pooled1 + (size_t)GCONST * 2 * OC1;
    float* pbn     = m1 + (size_t)GCONST * 1024;
    float* hbuf    = pbn + (size_t)GCONST * 512;
    float* meanb   = alloc(512);
    float* invb    = alloc(512);
    int*   starts0 = (int*)alloc(520);
    int*   starts1 = (int*)alloc(520);

    const int G = GCONST;

    // =========================== branch 0 (F=93) ===========================
    {
        const int N = N0, F = F0C, E = E0C, OC = OC0;
        find_starts_kernel<<<3, 256, 0, stream>>>(bat0, N, G, starts0);
        // --- CSR build (amortized over both conv layers) ---
        zero_int_kernel<<<ceildiv(N, 256), 256, 0, stream>>>(deg, N);
        hist_kernel<<<ceildiv(E, 256), 256, 0, stream>>>(ei0, E, deg);
        scan_kernel<<<1, 1024, 0, stream>>>(deg, N, E, rowptr, cursor);
        fill_kernel<<<ceildiv(E, 256), 256, 0, stream>>>(ei0, E, cursor, colb);
        // --- conv1: t = x + agg(x); y1 = relu(t @ w_c1 + b_c1) ---
        gather_agg_kernel<F0C, 128><<<ceildiv(N, 2), 256, 0, stream>>>(t, x0, rowptr, colb, N);
        gemm_bias_kernel<<<dim3(ceildiv(F, 64), ceildiv(N, 64)), 256, 0, stream>>>(
            t, w_c1, b_c1, y1, N, F, F, 1);
        // --- conv2 aggregate: t = y1 + agg(y1) ---
        gather_agg_kernel<F0C, 128><<<ceildiv(N, 2), 256, 0, stream>>>(t, y1, rowptr, colb, N);
        // --- fused conv2 matmul + relu + mean/max pool (CSR dead from here) ---
        conv2_pool_kernel<F0C><<<dim3(ceildiv(OC, 256), G), 256, 0, stream>>>(
            t, w_c2, b_c2, starts0, pooled0, OC);
        // --- MLP ---
        gemm_bias_kernel<<<dim3(1024 / 64, G / 64), 256, 0, stream>>>(
            pooled0, g0_w1, g0_b1, m1, G, 1024, 2 * OC, 1);
        gemm_bias_kernel<<<dim3(512 / 64, G / 64), 256, 0, stream>>>(
            m1, g0_w2, g0_b2, pbn, G, 512, 1024, 0);
        bn_stats_kernel<<<512, 256, 0, stream>>>(pbn, G, 512, meanb, invb);
        bn_apply_kernel<<<ceildiv(G * 512, 256), 256, 0, stream>>>(
            pbn, g0_bn_g, g0_bn_b, meanb, invb, out_xg0, G * 512, 512);
        // --- head ---
        gemm_bias_kernel<<<dim3(256 / 64, G / 64), 256, 0, stream>>>(
            out_xg0, f0_w1, f0_b1, hbuf, G, 256, 512, 1);
        gemm_bias_kernel<<<dim3(1, G / 64), 256, 0, stream>>>(
            hbuf, f0_w2, f0_b2, out_z, G, 2, 256, 0);
    }

    // =========================== branch 1 (F=43) ===========================
    {
        const int N = N1, F = F1C, E = E1C, OC = OC1;
        find_starts_kernel<<<3, 256, 0, stream>>>(bat1, N, G, starts1);
        zero_int_kernel<<<ceildiv(N, 256), 256, 0, stream>>>(deg, N);
        hist_kernel<<<ceildiv(E, 256), 256, 0, stream>>>(ei1, E, deg);
        scan_kernel<<<1, 1024, 0, stream>>>(deg, N, E, rowptr, cursor);
        fill_kernel<<<ceildiv(E, 256), 256, 0, stream>>>(ei1, E, cursor, colb);
        gather_agg_kernel<F1C, 64><<<ceildiv(N, 4), 256, 0, stream>>>(t, x1, rowptr, colb, N);
        gemm_bias_kernel<<<dim3(ceildiv(F, 64), ceildiv(N, 64)), 256, 0, stream>>>(
            t, w_c3, b_c3, y1, N, F, F, 1);
        gather_agg_kernel<F1C, 64><<<ceildiv(N, 4), 256, 0, stream>>>(t, y1, rowptr, colb, N);
        conv2_pool_kernel<F1C><<<dim3(ceildiv(OC, 256), G), 256, 0, stream>>>(
            t, w_c4, b_c4, starts1, pooled1, OC);
        gemm_bias_kernel<<<dim3(1024 / 64, G / 64), 256, 0, stream>>>(
            pooled1, g1_w1, g1_b1, m1, G, 1024, 2 * OC, 1);
        gemm_bias_kernel<<<dim3(512 / 64, G / 64), 256, 0, stream>>>(
            m1, g1_w2, g1_b2, pbn, G, 512, 1024, 0);
        bn_stats_kernel<<<512, 256, 0, stream>>>(pbn, G, 512, meanb, invb);
        bn_apply_kernel<<<ceildiv(G * 512, 256), 256, 0, stream>>>(
            pbn, g1_bn_g, g1_bn_b, meanb, invb, out_xg1, G * 512, 512);
        gemm_bias_kernel<<<dim3(256 / 64, G / 64), 256, 0, stream>>>(
            out_xg1, f1_w1, f1_b1, hbuf, G, 256, 512, 1);
        gemm_bias_kernel<<<dim3(1, G / 64), 256, 0, stream>>>(
            hbuf, f1_w2, f1_b2, out_z1, G, 2, 256, 0);
    }
}

// Round 3
// 3357.520 us; speedup vs baseline: 1.2326x; 1.1305x over previous
//
#include <hip/hip_runtime.h>
#include <hip/hip_bf16.h>

// ---------------------------------------------------------------------------
// Problem constants (from reference setup_inputs)
// ---------------------------------------------------------------------------
#define N0 100000
#define E0C 1600000
#define N1 100000
#define E1C 1600000
#define GCONST 512
#define F0C 93
#define F1C 43
#define OC0 (F0C * 10)   // 930
#define OC1 (F1C * 10)   // 430
#define BN_EPS 1e-5f

// ---------------------------------------------------------------------------
// zero ints
// ---------------------------------------------------------------------------
__global__ __launch_bounds__(256) void zero_int_kernel(int* __restrict__ p, int n) {
    int i = blockIdx.x * 256 + threadIdx.x;
    if (i < n) p[i] = 0;
}

// ---------------------------------------------------------------------------
// graph boundary search: starts[g] = lower_bound(batch, g); starts[G] = N
// ---------------------------------------------------------------------------
__global__ __launch_bounds__(256) void find_starts_kernel(const int* __restrict__ batch,
                                                          int N, int G,
                                                          int* __restrict__ starts) {
    int g = blockIdx.x * 256 + threadIdx.x;
    if (g > G) return;
    if (g == G) { starts[G] = N; return; }
    int lo = 0, hi = N;
    while (lo < hi) {
        int mid = (lo + hi) >> 1;
        if (batch[mid] < g) lo = mid + 1; else hi = mid;
    }
    starts[g] = lo;
}

// ---------------------------------------------------------------------------
// CSR build: histogram of dst, scan, fill col with src per dst bucket
// ---------------------------------------------------------------------------
__global__ __launch_bounds__(256) void hist_kernel(const int* __restrict__ ei,
                                                   int E, int* __restrict__ deg) {
    int e = blockIdx.x * 256 + threadIdx.x;
    if (e >= E) return;
    atomicAdd(&deg[ei[E + e]], 1);   // dst row
}

__global__ __launch_bounds__(1024) void scan_kernel(const int* __restrict__ deg,
                                                    int N, int E,
                                                    int* __restrict__ rowptr,
                                                    int* __restrict__ cursor) {
    __shared__ int part[1024];
    int tid = threadIdx.x;
    int chunk = (N + 1023) / 1024;
    int s = tid * chunk;
    int e = s + chunk < N ? s + chunk : N;
    int sum = 0;
    for (int i = s; i < e; ++i) sum += deg[i];
    part[tid] = sum;
    __syncthreads();
    // inclusive Hillis-Steele scan over partials
    for (int off = 1; off < 1024; off <<= 1) {
        int add = (tid >= off) ? part[tid - off] : 0;
        __syncthreads();
        part[tid] += add;
        __syncthreads();
    }
    int run = part[tid] - sum;  // exclusive prefix of this chunk
    for (int i = s; i < e; ++i) {
        rowptr[i] = run;
        cursor[i] = run;
        run += deg[i];
    }
    if (tid == 1023) rowptr[N] = E;
}

__global__ __launch_bounds__(256) void fill_kernel(const int* __restrict__ ei,
                                                   int E,
                                                   int* __restrict__ cursor,
                                                   int* __restrict__ col) {
    int e = blockIdx.x * 256 + threadIdx.x;
    if (e >= E) return;
    int src = ei[e];
    int dst = ei[E + e];
    int pos = atomicAdd(&cursor[dst], 1);
    col[pos] = src;
}

// ---------------------------------------------------------------------------
// CSR gather-aggregate: t[i] = x[i] + sum_{j in row(i)} x[col[j]]
// block = (256/FPAD) nodes x FPAD feature-lanes; coalesced row reads.
// ---------------------------------------------------------------------------
template<int F, int FPAD>
__global__ __launch_bounds__(256) void gather_agg_kernel(float* __restrict__ t,
                                                         const float* __restrict__ x,
                                                         const int* __restrict__ rowptr,
                                                         const int* __restrict__ col,
                                                         int N) {
    constexpr int NPB = 256 / FPAD;
    int node = blockIdx.x * NPB + threadIdx.x / FPAD;
    int f = threadIdx.x % FPAD;
    if (node >= N || f >= F) return;
    int s = rowptr[node], e = rowptr[node + 1];
    float a0 = x[(size_t)node * F + f];
    float a1 = 0.f, a2 = 0.f, a3 = 0.f;
    int j = s;
    for (; j + 3 < e; j += 4) {
        int s0 = col[j], s1 = col[j + 1], s2 = col[j + 2], s3 = col[j + 3];
        a0 += x[(size_t)s0 * F + f];
        a1 += x[(size_t)s1 * F + f];
        a2 += x[(size_t)s2 * F + f];
        a3 += x[(size_t)s3 * F + f];
    }
    for (; j < e; ++j) a0 += x[(size_t)col[j] * F + f];
    t[(size_t)node * F + f] = (a0 + a1) + (a2 + a3);
}

// ---------------------------------------------------------------------------
// generic fp32 GEMM: C = A[MxK] @ B[KxN] + bias, optional relu.
// 64x64 tile, 256 threads, 4x4 register micro-tile, K-tile 16.
// ---------------------------------------------------------------------------
__global__ __launch_bounds__(256) void gemm_bias_kernel(const float* __restrict__ A,
                                                        const float* __restrict__ B,
                                                        const float* __restrict__ bias,
                                                        float* __restrict__ C,
                                                        int M, int N, int K, int relu) {
    __shared__ float As[16][64];
    __shared__ float Bs[16][64];
    int tid = threadIdx.x;
    int tx = tid & 15, ty = tid >> 4;
    int m0 = blockIdx.y * 64, n0 = blockIdx.x * 64;
    float acc[4][4] = {};
    for (int k0 = 0; k0 < K; k0 += 16) {
#pragma unroll
        for (int i = 0; i < 4; ++i) {
            int lin = tid + i * 256;
            int m = lin >> 4, k = lin & 15;
            int gm = m0 + m, gk = k0 + k;
            As[k][m] = (gm < M && gk < K) ? A[(size_t)gm * K + gk] : 0.f;
        }
#pragma unroll
        for (int i = 0; i < 4; ++i) {
            int lin = tid + i * 256;
            int n = lin & 63, k = lin >> 6;
            int gn = n0 + n, gk = k0 + k;
            Bs[k][n] = (gk < K && gn < N) ? B[(size_t)gk * N + gn] : 0.f;
        }
        __syncthreads();
#pragma unroll
        for (int k = 0; k < 16; ++k) {
            float a[4], b[4];
#pragma unroll
            for (int i = 0; i < 4; ++i) a[i] = As[k][ty * 4 + i];
#pragma unroll
            for (int j = 0; j < 4; ++j) b[j] = Bs[k][tx * 4 + j];
#pragma unroll
            for (int i = 0; i < 4; ++i)
#pragma unroll
                for (int j = 0; j < 4; ++j)
                    acc[i][j] = fmaf(a[i], b[j], acc[i][j]);
        }
        __syncthreads();
    }
#pragma unroll
    for (int i = 0; i < 4; ++i) {
        int gm = m0 + ty * 4 + i;
        if (gm >= M) continue;
#pragma unroll
        for (int j = 0; j < 4; ++j) {
            int gn = n0 + tx * 4 + j;
            if (gn >= N) continue;
            float v = acc[i][j] + bias[gn];
            if (relu) v = fmaxf(v, 0.f);
            C[(size_t)gm * N + gn] = v;
        }
    }
}

// ---------------------------------------------------------------------------
// fused conv2 matmul + relu + mean/max pool.
// thread = output column, block.y = graph. W column in registers.
// __launch_bounds__(256, 2): VGPR cap 256 so the F-float weight column STAYS
// in VGPRs (at (256) default the compiler capped at 60 VGPRs and re-loaded W
// from L1 every node -> L1-bound, VALUBusy 30%).
// t-row reads are wave-uniform -> scalar loads feeding v_fmac v,s,v.
// pooled layout: [G][2*OC]  (mean | max)
// ---------------------------------------------------------------------------
template<int F>
__global__ __launch_bounds__(256, 2) void conv2_pool_kernel(const float* __restrict__ t,
                                                            const float* __restrict__ W,
                                                            const float* __restrict__ bias,
                                                            const int* __restrict__ starts,
                                                            float* __restrict__ pooled,
                                                            int OC) {
    int col = blockIdx.x * 256 + threadIdx.x;
    if (col >= OC) return;  // no barriers below; early exit safe
    int g = blockIdx.y;
    float wreg[F];
#pragma unroll
    for (int k = 0; k < F; ++k) wreg[k] = W[(size_t)k * OC + col];
    float bb = bias[col];
    int s = starts[g], e = starts[g + 1];
    float sum = 0.f, mx = 0.f;
    for (int n = s; n < e; ++n) {
        const float* __restrict__ tr = t + (size_t)n * F;
        float a0 = 0.f, a1 = 0.f, a2 = 0.f, a3 = 0.f;
#pragma unroll
        for (int k = 0; k + 3 < F; k += 4) {
            a0 = fmaf(wreg[k + 0], tr[k + 0], a0);
            a1 = fmaf(wreg[k + 1], tr[k + 1], a1);
            a2 = fmaf(wreg[k + 2], tr[k + 2], a2);
            a3 = fmaf(wreg[k + 3], tr[k + 3], a3);
        }
#pragma unroll
        for (int k = F & ~3; k < F; ++k) a0 = fmaf(wreg[k], tr[k], a0);
        float o = bb + (a0 + a1) + (a2 + a3);
        o = fmaxf(o, 0.f);
        sum += o;
        mx = fmaxf(mx, o);
    }
    int cnt = e - s;
    float mean = sum / (float)(cnt > 0 ? cnt : 1);
    size_t base = (size_t)g * (size_t)(2 * OC);
    pooled[base + col] = mean;
    pooled[base + OC + col] = mx;
}

// ---------------------------------------------------------------------------
// batchnorm stats + apply
// ---------------------------------------------------------------------------
__global__ __launch_bounds__(256) void bn_stats_kernel(const float* __restrict__ p,
                                                       int rows, int cols,
                                                       float* __restrict__ mean,
                                                       float* __restrict__ inv) {
    int c = blockIdx.x;
    float s = 0.f, s2 = 0.f;
    for (int r = threadIdx.x; r < rows; r += 256) {
        float v = p[(size_t)r * cols + c];
        s += v;
        s2 += v * v;
    }
    __shared__ float ls[256], ls2[256];
    ls[threadIdx.x] = s;
    ls2[threadIdx.x] = s2;
    __syncthreads();
    for (int st = 128; st > 0; st >>= 1) {
        if (threadIdx.x < st) {
            ls[threadIdx.x] += ls[threadIdx.x + st];
            ls2[threadIdx.x] += ls2[threadIdx.x + st];
        }
        __syncthreads();
    }
    if (threadIdx.x == 0) {
        float m = ls[0] / (float)rows;
        float var = ls2[0] / (float)rows - m * m;
        mean[c] = m;
        inv[c] = 1.f / sqrtf(var + BN_EPS);
    }
}

__global__ __launch_bounds__(256) void bn_apply_kernel(const float* __restrict__ p,
                                                       const float* __restrict__ gamma,
                                                       const float* __restrict__ beta,
                                                       const float* __restrict__ mean,
                                                       const float* __restrict__ inv,
                                                       float* __restrict__ outp,
                                                       int total, int cols) {
    int i = blockIdx.x * 256 + threadIdx.x;
    if (i >= total) return;
    int c = i & (cols - 1);  // cols = 512 (pow2)
    outp[i] = gamma[c] * (p[i] - mean[c]) * inv[c] + beta[c];
}

// ---------------------------------------------------------------------------
// launch
// ---------------------------------------------------------------------------
static inline int ceildiv(int a, int b) { return (a + b - 1) / b; }

extern "C" void kernel_launch(void* const* d_in, const int* in_sizes, int n_in,
                              void* d_out, int out_size, void* d_ws, size_t ws_size,
                              hipStream_t stream) {
    const float* x0   = (const float*)d_in[0];
    const float* x1   = (const float*)d_in[1];
    const int*   ei0  = (const int*)d_in[2];
    const int*   ei1  = (const int*)d_in[3];
    const int*   bat0 = (const int*)d_in[4];
    const int*   bat1 = (const int*)d_in[5];
    const float* w_c1 = (const float*)d_in[6];
    const float* b_c1 = (const float*)d_in[7];
    const float* w_c2 = (const float*)d_in[8];
    const float* b_c2 = (const float*)d_in[9];
    const float* w_c3 = (const float*)d_in[10];
    const float* b_c3 = (const float*)d_in[11];
    const float* w_c4 = (const float*)d_in[12];
    const float* b_c4 = (const float*)d_in[13];
    const float* g0_w1 = (const float*)d_in[14];
    const float* g0_b1 = (const float*)d_in[15];
    const float* g0_w2 = (const float*)d_in[16];
    const float* g0_b2 = (const float*)d_in[17];
    const float* g0_bn_g = (const float*)d_in[18];
    const float* g0_bn_b = (const float*)d_in[19];
    const float* g1_w1 = (const float*)d_in[20];
    const float* g1_b1 = (const float*)d_in[21];
    const float* g1_w2 = (const float*)d_in[22];
    const float* g1_b2 = (const float*)d_in[23];
    const float* g1_bn_g = (const float*)d_in[24];
    const float* g1_bn_b = (const float*)d_in[25];
    const float* f0_w1 = (const float*)d_in[26];
    const float* f0_b1 = (const float*)d_in[27];
    const float* f0_w2 = (const float*)d_in[28];
    const float* f0_b2 = (const float*)d_in[29];
    const float* f1_w1 = (const float*)d_in[30];
    const float* f1_b1 = (const float*)d_in[31];
    const float* f1_w2 = (const float*)d_in[32];
    const float* f1_b2 = (const float*)d_in[33];

    float* out = (float*)d_out;
    // d_out layout: z [512*2] | x_g_0 [512*512] | x_g_1 [512*512] | z1 [512*2]
    float* out_z   = out;
    float* out_xg0 = out + 1024;
    float* out_xg1 = out + 1024 + 262144;
    float* out_z1  = out + 1024 + 262144 + 262144;

    // workspace carve (floats)
    float* ws = (float*)d_ws;
    size_t off = 0;
    auto alloc = [&](size_t n) { float* p = ws + off; off += n; return p; };
    float* t  = alloc((size_t)N0 * F0C);   // 9.3M
    float* y1 = alloc((size_t)N0 * F0C);   // 9.3M
    // Union region C: CSR (graph phase) aliases MLP temps (dense phase).
    // CSR is dead before conv2_pool writes pooled -> safe.
    size_t csr_floats = (size_t)N0 + (N0 + 1) + N0 + E0C;        // 1.90M
    size_t mlp_floats = (size_t)GCONST * 2 * OC0 + (size_t)GCONST * 2 * OC1 +
                        (size_t)GCONST * 1024 + (size_t)GCONST * 512 +
                        (size_t)GCONST * 256;                     // 2.31M
    float* regionC = alloc(csr_floats > mlp_floats ? csr_floats : mlp_floats);
    int* deg    = (int*)regionC;
    int* rowptr = deg + N0;
    int* cursor = rowptr + (N0 + 1);
    int* colb   = cursor + N0;
    float* pooled0 = regionC;
    float* pooled1 = pooled0 + (size_t)GCONST * 2 * OC0;
    float* m1      = pooled1 + (size_t)GCONST * 2 * OC1;
    float* pbn     = m1 + (size_t)GCONST * 1024;
    float* hbuf    = pbn + (size_t)GCONST * 512;
    float* meanb   = alloc(512);
    float* invb    = alloc(512);
    int*   starts0 = (int*)alloc(520);
    int*   starts1 = (int*)alloc(520);

    const int G = GCONST;

    // =========================== branch 0 (F=93) ===========================
    {
        const int N = N0, F = F0C, E = E0C, OC = OC0;
        find_starts_kernel<<<3, 256, 0, stream>>>(bat0, N, G, starts0);
        // --- CSR build (amortized over both conv layers) ---
        zero_int_kernel<<<ceildiv(N, 256), 256, 0, stream>>>(deg, N);
        hist_kernel<<<ceildiv(E, 256), 256, 0, stream>>>(ei0, E, deg);
        scan_kernel<<<1, 1024, 0, stream>>>(deg, N, E, rowptr, cursor);
        fill_kernel<<<ceildiv(E, 256), 256, 0, stream>>>(ei0, E, cursor, colb);
        // --- conv1: t = x + agg(x); y1 = relu(t @ w_c1 + b_c1) ---
        gather_agg_kernel<F0C, 128><<<ceildiv(N, 2), 256, 0, stream>>>(t, x0, rowptr, colb, N);
        gemm_bias_kernel<<<dim3(ceildiv(F, 64), ceildiv(N, 64)), 256, 0, stream>>>(
            t, w_c1, b_c1, y1, N, F, F, 1);
        // --- conv2 aggregate: t = y1 + agg(y1) ---
        gather_agg_kernel<F0C, 128><<<ceildiv(N, 2), 256, 0, stream>>>(t, y1, rowptr, colb, N);
        // --- fused conv2 matmul + relu + mean/max pool (CSR dead from here) ---
        conv2_pool_kernel<F0C><<<dim3(ceildiv(OC, 256), G), 256, 0, stream>>>(
            t, w_c2, b_c2, starts0, pooled0, OC);
        // --- MLP ---
        gemm_bias_kernel<<<dim3(1024 / 64, G / 64), 256, 0, stream>>>(
            pooled0, g0_w1, g0_b1, m1, G, 1024, 2 * OC, 1);
        gemm_bias_kernel<<<dim3(512 / 64, G / 64), 256, 0, stream>>>(
            m1, g0_w2, g0_b2, pbn, G, 512, 1024, 0);
        bn_stats_kernel<<<512, 256, 0, stream>>>(pbn, G, 512, meanb, invb);
        bn_apply_kernel<<<ceildiv(G * 512, 256), 256, 0, stream>>>(
            pbn, g0_bn_g, g0_bn_b, meanb, invb, out_xg0, G * 512, 512);
        // --- head ---
        gemm_bias_kernel<<<dim3(256 / 64, G / 64), 256, 0, stream>>>(
            out_xg0, f0_w1, f0_b1, hbuf, G, 256, 512, 1);
        gemm_bias_kernel<<<dim3(1, G / 64), 256, 0, stream>>>(
            hbuf, f0_w2, f0_b2, out_z, G, 2, 256, 0);
    }

    // =========================== branch 1 (F=43) ===========================
    {
        const int N = N1, F = F1C, E = E1C, OC = OC1;
        find_starts_kernel<<<3, 256, 0, stream>>>(bat1, N, G, starts1);
        zero_int_kernel<<<ceildiv(N, 256), 256, 0, stream>>>(deg, N);
        hist_kernel<<<ceildiv(E, 256), 256, 0, stream>>>(ei1, E, deg);
        scan_kernel<<<1, 1024, 0, stream>>>(deg, N, E, rowptr, cursor);
        fill_kernel<<<ceildiv(E, 256), 256, 0, stream>>>(ei1, E, cursor, colb);
        gather_agg_kernel<F1C, 64><<<ceildiv(N, 4), 256, 0, stream>>>(t, x1, rowptr, colb, N);
        gemm_bias_kernel<<<dim3(ceildiv(F, 64), ceildiv(N, 64)), 256, 0, stream>>>(
            t, w_c3, b_c3, y1, N, F, F, 1);
        gather_agg_kernel<F1C, 64><<<ceildiv(N, 4), 256, 0, stream>>>(t, y1, rowptr, colb, N);
        conv2_pool_kernel<F1C><<<dim3(ceildiv(OC, 256), G), 256, 0, stream>>>(
            t, w_c4, b_c4, starts1, pooled1, OC);
        gemm_bias_kernel<<<dim3(1024 / 64, G / 64), 256, 0, stream>>>(
            pooled1, g1_w1, g1_b1, m1, G, 1024, 2 * OC, 1);
        gemm_bias_kernel<<<dim3(512 / 64, G / 64), 256, 0, stream>>>(
            m1, g1_w2, g1_b2, pbn, G, 512, 1024, 0);
        bn_stats_kernel<<<512, 256, 0, stream>>>(pbn, G, 512, meanb, invb);
        bn_apply_kernel<<<ceildiv(G * 512, 256), 256, 0, stream>>>(
            pbn, g1_bn_g, g1_bn_b, meanb, invb, out_xg1, G * 512, 512);
        gemm_bias_kernel<<<dim3(256 / 64, G / 64), 256, 0, stream>>>(
            out_xg1, f1_w1, f1_b1, hbuf, G, 256, 512, 1);
        gemm_bias_kernel<<<dim3(1, G / 64), 256, 0, stream>>>(
            hbuf, f1_w2, f1_b2, out_z1, G, 2, 256, 0);
    }
}